// Round 4
// baseline (1600.374 us; speedup 1.0000x reference)
//
#include <hip/hip_runtime.h>
#include <stdint.h>

#define SEQ    2048
#define DMODEL 2048
#define NTOK   4096   // B*S
#define NHEAD  16
#define NKVH   4
#define HDIM   128
#define FFDIM  7168

typedef __bf16 bf16x8 __attribute__((ext_vector_type(8)));
typedef float  floatx4 __attribute__((ext_vector_type(4)));

__device__ __forceinline__ float bf2f(unsigned short u) {
  union { unsigned int i; float f; } v; v.i = ((unsigned int)u) << 16; return v.f;
}
__device__ __forceinline__ unsigned short f2bf(float f) {
  union { float f; unsigned int u; } v; v.f = f;
  unsigned int r = (v.u + 0x7FFFu + ((v.u >> 16) & 1u)) >> 16;
  return (unsigned short)r;
}
// 8 bf16 elements (16B) from bf16 memory
__device__ __forceinline__ uint4 ld8bf(const unsigned short* p) { return *(const uint4*)p; }
// 8 f32 elements (32B) from f32 memory, converted to 8 bf16 (16B)
__device__ __forceinline__ uint4 ld8f32(const float* p) {
  float4 a = *(const float4*)p, b = *(const float4*)(p + 4);
  union { unsigned short s[8]; uint4 v; } o;
  o.s[0] = f2bf(a.x); o.s[1] = f2bf(a.y); o.s[2] = f2bf(a.z); o.s[3] = f2bf(a.w);
  o.s[4] = f2bf(b.x); o.s[5] = f2bf(b.y); o.s[6] = f2bf(b.z); o.s[7] = f2bf(b.w);
  return o.v;
}

// ======== GEMM core: 128x128 tile, BK=32, 4 waves, A bf16 / W f32 ==============
#define GEMM_PROLOG(Aptr, Wptr)                                                  \
  __shared__ __align__(16) unsigned short As[128 * 32];                          \
  __shared__ __align__(16) unsigned short Bs[128 * 32];                          \
  const int tid  = threadIdx.x;                                                  \
  const int wave = tid >> 6, lane = tid & 63;                                    \
  const int quad = lane >> 4, l16 = lane & 15;                                   \
  const int row0 = blockIdx.y * 128, col0 = blockIdx.x * 128;                    \
  const int wm = (wave >> 1) * 64, wn = (wave & 1) * 64;                         \
  const floatx4 z = {0.f, 0.f, 0.f, 0.f};                                       \
  floatx4 acc[4][4];                                                             \
  _Pragma("unroll") for (int i = 0; i < 4; ++i)                                  \
  _Pragma("unroll") for (int j = 0; j < 4; ++j) acc[i][j] = z;                   \
  for (int k0 = 0; k0 < K; k0 += 32) {                                           \
    uint4 staA[2], staB[2];                                                      \
    _Pragma("unroll") for (int it = 0; it < 2; ++it) {                           \
      const int chunk = it * 256 + tid;                                          \
      const int r = chunk >> 2, c = (chunk & 3) << 3;                            \
      staA[it] = ld8bf(Aptr + (size_t)(row0 + r) * K + k0 + c);                  \
      staB[it] = ld8f32(Wptr + (size_t)(col0 + r) * K + k0 + c);                 \
    }                                                                            \
    _Pragma("unroll") for (int it = 0; it < 2; ++it) {                           \
      const int chunk = it * 256 + tid;                                          \
      *(uint4*)&As[chunk * 8] = staA[it];                                        \
      *(uint4*)&Bs[chunk * 8] = staB[it];                                        \
    }                                                                            \
    __syncthreads();                                                             \
    bf16x8 af[4], bfr[4];                                                        \
    _Pragma("unroll") for (int i = 0; i < 4; ++i) {                              \
      af[i]  = *(const bf16x8*)&As[(wm + i * 16 + l16) * 32 + quad * 8];         \
      bfr[i] = *(const bf16x8*)&Bs[(wn + i * 16 + l16) * 32 + quad * 8];         \
    }                                                                            \
    _Pragma("unroll") for (int mi = 0; mi < 4; ++mi)                             \
    _Pragma("unroll") for (int ni = 0; ni < 4; ++ni)                             \
      acc[mi][ni] =                                                              \
          __builtin_amdgcn_mfma_f32_16x16x32_bf16(af[mi], bfr[ni], acc[mi][ni], 0, 0, 0); \
    __syncthreads();                                                             \
  }

// C[M,N] = A[M,K] * W[N,K]^T, A bf16, W f32, C bf16
__global__ __launch_bounds__(256) void gemm_bt(
    const unsigned short* __restrict__ A, const float* __restrict__ W,
    unsigned short* __restrict__ C, int M, int N, int K) {
  GEMM_PROLOG(A, W)
#pragma unroll
  for (int mi = 0; mi < 4; ++mi) {
    const int r = row0 + wm + mi * 16 + quad * 4;
#pragma unroll
    for (int ni = 0; ni < 4; ++ni) {
      const int cc = col0 + wn + ni * 16 + l16;
#pragma unroll
      for (int reg = 0; reg < 4; ++reg)
        C[(size_t)(r + reg) * N + cc] = f2bf(acc[mi][ni][reg]);
    }
  }
}

// o-proj + residual: h (f32) = x (f32) + A*W^T
__global__ __launch_bounds__(256) void gemm_o_res(
    const unsigned short* __restrict__ A, const float* __restrict__ W,
    const float* __restrict__ X, float* __restrict__ Hout,
    int M, int N, int K) {
  GEMM_PROLOG(A, W)
#pragma unroll
  for (int mi = 0; mi < 4; ++mi) {
    const int r = row0 + wm + mi * 16 + quad * 4;
#pragma unroll
    for (int ni = 0; ni < 4; ++ni) {
      const int cc = col0 + wn + ni * 16 + l16;
#pragma unroll
      for (int reg = 0; reg < 4; ++reg) {
        const size_t idx = (size_t)(r + reg) * N + cc;
        Hout[idx] = X[idx] + acc[mi][ni][reg];
      }
    }
  }
}

// down-proj + MoD epilogue: out (f32) = h + (mask ? scv * (A*W^T) : 0)
__global__ __launch_bounds__(256) void gemm_down_mod(
    const unsigned short* __restrict__ A, const float* __restrict__ W,
    const float* __restrict__ H, const int* __restrict__ mask,
    const float* __restrict__ ts, float* __restrict__ out,
    int M, int N, int K) {
  GEMM_PROLOG(A, W)
#pragma unroll
  for (int mi = 0; mi < 4; ++mi) {
    const int r = row0 + wm + mi * 16 + quad * 4;
#pragma unroll
    for (int ni = 0; ni < 4; ++ni) {
      const int cc = col0 + wn + ni * 16 + l16;
#pragma unroll
      for (int reg = 0; reg < 4; ++reg) {
        const int rr = r + reg;
        const float scv = 0.5f + (ts[rr] - 0.5f) * 0.7f;
        const float upd = mask[rr] ? acc[mi][ni][reg] * scv : 0.f;
        out[(size_t)rr * N + cc] = H[(size_t)rr * N + cc] + upd;
      }
    }
  }
}

// fused gate+up GEMM with silu(g)*u epilogue. Tile: 128 rows x 64 cols of BOTH.
__global__ __launch_bounds__(256) void gemm_gateup(
    const unsigned short* __restrict__ A, const float* __restrict__ G,
    const float* __restrict__ U, unsigned short* __restrict__ act,
    int M, int K) {
  __shared__ __align__(16) unsigned short As[128 * 32];
  __shared__ __align__(16) unsigned short Bgs[64 * 32];
  __shared__ __align__(16) unsigned short Bus[64 * 32];
  const int tid  = threadIdx.x;
  const int wave = tid >> 6, lane = tid & 63;
  const int quad = lane >> 4, l16 = lane & 15;
  const int row0 = blockIdx.y * 128, colg = blockIdx.x * 64;
  const int wm = (wave >> 1) * 64, wn = (wave & 1) * 32;

  const floatx4 z = {0.f, 0.f, 0.f, 0.f};
  floatx4 accG[4][2], accU[4][2];
#pragma unroll
  for (int i = 0; i < 4; ++i)
#pragma unroll
    for (int j = 0; j < 2; ++j) { accG[i][j] = z; accU[i][j] = z; }

  for (int k0 = 0; k0 < K; k0 += 32) {
    uint4 stA0, stA1, stG, stU;
    {
      const int r0 = tid >> 2, c0 = (tid & 3) << 3;
      stA0 = ld8bf(A + (size_t)(row0 + r0) * K + k0 + c0);
      const int chunk = 256 + tid;
      const int r1 = chunk >> 2, c1 = (chunk & 3) << 3;
      stA1 = ld8bf(A + (size_t)(row0 + r1) * K + k0 + c1);
      stG = ld8f32(G + (size_t)(colg + r0) * K + k0 + c0);
      stU = ld8f32(U + (size_t)(colg + r0) * K + k0 + c0);
    }
    {
      *(uint4*)&As[tid * 8] = stA0;
      *(uint4*)&As[(256 + tid) * 8] = stA1;
      *(uint4*)&Bgs[tid * 8] = stG;
      *(uint4*)&Bus[tid * 8] = stU;
    }
    __syncthreads();
    bf16x8 af[4], bg[2], bu[2];
#pragma unroll
    for (int i = 0; i < 4; ++i)
      af[i] = *(const bf16x8*)&As[(wm + i * 16 + l16) * 32 + quad * 8];
#pragma unroll
    for (int j = 0; j < 2; ++j) {
      bg[j] = *(const bf16x8*)&Bgs[(wn + j * 16 + l16) * 32 + quad * 8];
      bu[j] = *(const bf16x8*)&Bus[(wn + j * 16 + l16) * 32 + quad * 8];
    }
#pragma unroll
    for (int mi = 0; mi < 4; ++mi)
#pragma unroll
      for (int ni = 0; ni < 2; ++ni) {
        accG[mi][ni] = __builtin_amdgcn_mfma_f32_16x16x32_bf16(af[mi], bg[ni], accG[mi][ni], 0, 0, 0);
        accU[mi][ni] = __builtin_amdgcn_mfma_f32_16x16x32_bf16(af[mi], bu[ni], accU[mi][ni], 0, 0, 0);
      }
    __syncthreads();
  }
#pragma unroll
  for (int mi = 0; mi < 4; ++mi) {
    const int r = row0 + wm + mi * 16 + quad * 4;
#pragma unroll
    for (int ni = 0; ni < 2; ++ni) {
      const int cc = colg + wn + ni * 16 + l16;
#pragma unroll
      for (int reg = 0; reg < 4; ++reg) {
        const float g = accG[mi][ni][reg];
        const float u = accU[mi][ni][reg];
        const float s = g / (1.f + __expf(-g));
        act[(size_t)(r + reg) * FFDIM + cc] = f2bf(s * u);
      }
    }
  }
}

// ---------------- RMSNorm: f32 in, f32 weight, bf16 out -------------------------
__global__ __launch_bounds__(256) void rmsnorm_f32(
    const float* __restrict__ x, const float* __restrict__ w,
    unsigned short* __restrict__ out) {
  __shared__ float red[4];
  const int row = blockIdx.x, tid = threadIdx.x;
  const int lane = tid & 63, wave = tid >> 6;
  const size_t base = (size_t)row * DMODEL + tid * 8;
  float4 a = *(const float4*)(x + base);
  float4 b = *(const float4*)(x + base + 4);
  float v[8] = {a.x, a.y, a.z, a.w, b.x, b.y, b.z, b.w};
  float ss = 0.f;
#pragma unroll
  for (int j = 0; j < 8; ++j) ss += v[j] * v[j];
#pragma unroll
  for (int off = 32; off; off >>= 1) ss += __shfl_xor(ss, off);
  if (lane == 0) red[wave] = ss;
  __syncthreads();
  const float tot = red[0] + red[1] + red[2] + red[3];
  const float rms = rsqrtf(tot * (1.f / (float)DMODEL) + 1e-5f);
  float4 wa = *(const float4*)(w + tid * 8);
  float4 wb = *(const float4*)(w + tid * 8 + 4);
  const float wv[8] = {wa.x, wa.y, wa.z, wa.w, wb.x, wb.y, wb.z, wb.w};
  unsigned short o[8];
#pragma unroll
  for (int j = 0; j < 8; ++j) o[j] = f2bf(v[j] * rms * wv[j]);
  *(uint4*)(out + base) = *(const uint4*)o;
}

// ---------------- RoPE in-place on [NTOK][nh*128] (bf16) ------------------------
__global__ __launch_bounds__(256) void rope_k(unsigned short* __restrict__ buf, int nh) {
  const int t = blockIdx.x;
  const int s = t & (SEQ - 1);
  const int npair = nh * 64;
  for (int idx = threadIdx.x; idx < npair; idx += 256) {
    const int hh = idx >> 6, d = idx & 63;
    const float inv = powf(10000.f, -(float)d * (1.f / 64.f));
    const float ang = (float)s * inv;
    const float cs = cosf(ang), sn = sinf(ang);
    unsigned short* p = buf + (size_t)t * (nh * 128) + hh * 128 + d;
    const float x1 = bf2f(p[0]), x2 = bf2f(p[64]);
    p[0]  = f2bf(x1 * cs - x2 * sn);
    p[64] = f2bf(x2 * cs + x1 * sn);
  }
}

// ---------------- Flash attention, causal, GQA rep=4 (bf16 in/out) --------------
__global__ __launch_bounds__(256) void attn(
    const unsigned short* __restrict__ Q,
    const unsigned short* __restrict__ K,
    const unsigned short* __restrict__ V,
    unsigned short* __restrict__ O) {
  __shared__ __align__(16) unsigned short Ks[64 * 136];
  __shared__ __align__(16) unsigned short Vt[128 * 80];
  __shared__ __align__(16) unsigned short Ps[4][16 * 80];
  const int qt = blockIdx.x, h = blockIdx.y, b = blockIdx.z;
  const int kvh = h >> 2;
  const int tid = threadIdx.x, wave = tid >> 6, lane = tid & 63;
  const int quad = lane >> 4, l16 = lane & 15;
  const int qbase = qt * 64;

  bf16x8 qf[4];
  {
    const unsigned short* qp =
        Q + (size_t)(b * SEQ + qbase + wave * 16 + l16) * (NHEAD * HDIM) + h * HDIM + quad * 8;
#pragma unroll
    for (int c = 0; c < 4; ++c) qf[c] = *(const bf16x8*)(qp + 32 * c);
  }
  const floatx4 z = {0.f, 0.f, 0.f, 0.f};
  floatx4 accO[8];
#pragma unroll
  for (int i = 0; i < 8; ++i) accO[i] = z;
  float mrow[4], lrow[4];
#pragma unroll
  for (int r = 0; r < 4; ++r) { mrow[r] = -1e30f; lrow[r] = 0.f; }
  const int qrowC = qbase + wave * 16 + quad * 4;
  const float sscale = 0.08838834764831845f;  // 1/sqrt(128)

  for (int t0 = 0; t0 <= qbase; t0 += 64) {
#pragma unroll
    for (int it = 0; it < 4; ++it) {
      const int chunk = tid + it * 256;
      const int r = chunk >> 4, c = (chunk & 15) * 8;
      *(uint4*)&Ks[r * 136 + c] =
          *(const uint4*)(K + (size_t)(b * SEQ + t0 + r) * (NKVH * HDIM) + kvh * HDIM + c);
    }
#pragma unroll
    for (int it = 0; it < 4; ++it) {
      const int chunk = tid + it * 256;
      const int i = chunk >> 4, c = (chunk & 15) * 8;
      uint4 dv = *(const uint4*)(V + (size_t)(b * SEQ + t0 + i) * (NKVH * HDIM) + kvh * HDIM + c);
      const unsigned short* dsv = (const unsigned short*)&dv;
#pragma unroll
      for (int j = 0; j < 8; ++j) Vt[(c + j) * 80 + i] = dsv[j];
    }
    __syncthreads();

    floatx4 sc[4];
#pragma unroll
    for (int ni = 0; ni < 4; ++ni) {
      floatx4 s = z;
#pragma unroll
      for (int c = 0; c < 4; ++c) {
        bf16x8 kf = *(const bf16x8*)&Ks[(ni * 16 + l16) * 136 + c * 32 + quad * 8];
        s = __builtin_amdgcn_mfma_f32_16x16x32_bf16(qf[c], kf, s, 0, 0, 0);
      }
      sc[ni] = s;
    }
#pragma unroll
    for (int ni = 0; ni < 4; ++ni) {
      const int kcol = t0 + ni * 16 + l16;
#pragma unroll
      for (int reg = 0; reg < 4; ++reg) {
        const float vv = sc[ni][reg] * sscale;
        sc[ni][reg] = (kcol > qrowC + reg) ? -1e30f : vv;
      }
    }
#pragma unroll
    for (int reg = 0; reg < 4; ++reg) {
      float mx = fmaxf(fmaxf(sc[0][reg], sc[1][reg]), fmaxf(sc[2][reg], sc[3][reg]));
#pragma unroll
      for (int off = 1; off < 16; off <<= 1) mx = fmaxf(mx, __shfl_xor(mx, off));
      const float mnew = fmaxf(mrow[reg], mx);
      const float alpha = __expf(mrow[reg] - mnew);
      mrow[reg] = mnew;
      float rs = 0.f;
#pragma unroll
      for (int ni = 0; ni < 4; ++ni) {
        const float p = __expf(sc[ni][reg] - mnew);
        sc[ni][reg] = p;
        rs += p;
      }
#pragma unroll
      for (int off = 1; off < 16; off <<= 1) rs += __shfl_xor(rs, off);
      lrow[reg] = lrow[reg] * alpha + rs;
#pragma unroll
      for (int nd = 0; nd < 8; ++nd) accO[nd][reg] *= alpha;
    }
#pragma unroll
    for (int ni = 0; ni < 4; ++ni)
#pragma unroll
      for (int reg = 0; reg < 4; ++reg)
        Ps[wave][(quad * 4 + reg) * 80 + ni * 16 + l16] = f2bf(sc[ni][reg]);
    __syncthreads();
    const bf16x8 pa0 = *(const bf16x8*)&Ps[wave][l16 * 80 + quad * 8];
    const bf16x8 pa1 = *(const bf16x8*)&Ps[wave][l16 * 80 + 32 + quad * 8];
#pragma unroll
    for (int nd = 0; nd < 8; ++nd) {
      bf16x8 v0 = *(const bf16x8*)&Vt[(nd * 16 + l16) * 80 + quad * 8];
      bf16x8 v1 = *(const bf16x8*)&Vt[(nd * 16 + l16) * 80 + 32 + quad * 8];
      accO[nd] = __builtin_amdgcn_mfma_f32_16x16x32_bf16(pa0, v0, accO[nd], 0, 0, 0);
      accO[nd] = __builtin_amdgcn_mfma_f32_16x16x32_bf16(pa1, v1, accO[nd], 0, 0, 0);
    }
    __syncthreads();
  }
#pragma unroll
  for (int nd = 0; nd < 8; ++nd)
#pragma unroll
    for (int reg = 0; reg < 4; ++reg) {
      const float o = accO[nd][reg] / lrow[reg];
      O[(size_t)(b * SEQ + qrowC + reg) * (NHEAD * HDIM) + h * HDIM + nd * 16 + l16] = f2bf(o);
    }
}

// ---------------- launch --------------------------------------------------------
extern "C" void kernel_launch(void* const* d_in, const int* in_sizes, int n_in,
                              void* d_out, int out_size, void* d_ws, size_t ws_size,
                              hipStream_t stream) {
  (void)in_sizes; (void)n_in; (void)out_size; (void)ws_size;
  const float* x    = (const float*)d_in[0];
  const int*   mask = (const int*)d_in[1];
  const float* ts   = (const float*)d_in[2];
  const float* ln1  = (const float*)d_in[3];
  const float* ln2  = (const float*)d_in[4];
  const float* q_w  = (const float*)d_in[5];
  const float* k_w  = (const float*)d_in[6];
  const float* v_w  = (const float*)d_in[7];
  const float* o_w  = (const float*)d_in[8];
  const float* g_w  = (const float*)d_in[9];
  const float* u_w  = (const float*)d_in[10];
  const float* dn_w = (const float*)d_in[11];
  float* out = (float*)d_out;

  // workspace layout (109 MB; act overlays dead q/k/v/attn buffers)
  char* ws = (char*)d_ws;
  unsigned short* xn    = (unsigned short*)(ws + 0);          // [0, 16.78 MB) bf16
  unsigned short* qb    = (unsigned short*)(ws + 16777216);   // [16.78, 33.55)
  unsigned short* kb    = (unsigned short*)(ws + 33554432);   // [33.55, 37.75)
  unsigned short* vb    = (unsigned short*)(ws + 37748736);   // [37.75, 41.94)
  unsigned short* attno = (unsigned short*)(ws + 41943040);   // [41.94, 58.72)
  unsigned short* act   = (unsigned short*)(ws + 16777216);   // [16.78, 75.50) overlays qb..attno
  float*          hbuf  = (float*)         (ws + 75497472);   // [75.50, 109.05) f32 residual

  rmsnorm_f32<<<NTOK, 256, 0, stream>>>(x, ln1, xn);
  gemm_bt<<<dim3(2048 / 128, NTOK / 128), 256, 0, stream>>>(xn, q_w, qb, NTOK, 2048, 2048);
  gemm_bt<<<dim3(512 / 128,  NTOK / 128), 256, 0, stream>>>(xn, k_w, kb, NTOK, 512, 2048);
  gemm_bt<<<dim3(512 / 128,  NTOK / 128), 256, 0, stream>>>(xn, v_w, vb, NTOK, 512, 2048);
  rope_k<<<NTOK, 256, 0, stream>>>(qb, NHEAD);
  rope_k<<<NTOK, 256, 0, stream>>>(kb, NKVH);
  attn<<<dim3(SEQ / 64, NHEAD, 2), 256, 0, stream>>>(qb, kb, vb, attno);
  gemm_o_res<<<dim3(2048 / 128, NTOK / 128), 256, 0, stream>>>(attno, o_w, x, hbuf, NTOK, 2048, 2048);
  rmsnorm_f32<<<NTOK, 256, 0, stream>>>(hbuf, ln2, xn);
  gemm_gateup<<<dim3(FFDIM / 64, NTOK / 128), 256, 0, stream>>>(xn, g_w, u_w, act, NTOK, 2048);
  gemm_down_mod<<<dim3(2048 / 128, NTOK / 128), 256, 0, stream>>>(act, dn_w, hbuf, mask, ts, out,
                                                                 NTOK, 2048, FFDIM);
}